// Round 1
// baseline (517.647 us; speedup 1.0000x reference)
//
#include <hip/hip_runtime.h>

typedef _Float16 f16x8 __attribute__((ext_vector_type(8)));
typedef float f32x4 __attribute__((ext_vector_type(4)));

#define EMB 768
#define HID 768
#define LQ 128
#define LD 1024
#define NB 32

// ---------- prep: W f32 -> f16 ----------
__global__ void cvt_w_kernel(const float* __restrict__ W, _Float16* __restrict__ W16, int n) {
    int i = blockIdx.x * 256 + threadIdx.x;
    if (i < n) W16[i] = (_Float16)W[i];
}

// ---------- prep: VT[b][e][q] = query_embed[b][q][e] (f16) ----------
__global__ void make_vt_kernel(const float* __restrict__ Q, _Float16* __restrict__ VT) {
    int i = blockIdx.x * 256 + threadIdx.x;
    if (i >= NB * EMB * LQ) return;
    int q = i % LQ;
    int e = (i / LQ) % EMB;
    int b = i / (LQ * EMB);
    VT[i] = (_Float16)Q[((size_t)b * LQ + q) * EMB + e];
}

// ---------- shared projection: OUT[m,h] = relu(sum_e X[m,e]*W[h,e] + b[h]) ----------
// grid: (M/64, HID/128), block 256 (4 waves). Wave w owns rows m0+w*16..+15.
__global__ __launch_bounds__(256) void proj_relu_kernel(
    const float* __restrict__ X, const _Float16* __restrict__ W16,
    const float* __restrict__ bias, _Float16* __restrict__ OUT) {
    const int wave = threadIdx.x >> 6;
    const int lane = threadIdx.x & 63;
    const int lr = lane & 15;          // A/B fragment row; C col
    const int lk = (lane >> 4) * 8;    // k offset within 32-wide K step
    const int m0 = blockIdx.x * 64 + wave * 16;
    const int n0 = blockIdx.y * 128;

    f32x4 acc[8];
#pragma unroll
    for (int t = 0; t < 8; ++t) acc[t] = (f32x4){0.f, 0.f, 0.f, 0.f};

    const float* xrow = X + (size_t)(m0 + lr) * EMB;
    for (int k0 = 0; k0 < EMB; k0 += 32) {
        const float4 xa = *(const float4*)(xrow + k0 + lk);
        const float4 xb = *(const float4*)(xrow + k0 + lk + 4);
        f16x8 a;
        a[0] = (_Float16)xa.x; a[1] = (_Float16)xa.y;
        a[2] = (_Float16)xa.z; a[3] = (_Float16)xa.w;
        a[4] = (_Float16)xb.x; a[5] = (_Float16)xb.y;
        a[6] = (_Float16)xb.z; a[7] = (_Float16)xb.w;
#pragma unroll
        for (int t = 0; t < 8; ++t) {
            const f16x8 bf = *(const f16x8*)(W16 + (size_t)(n0 + t * 16 + lr) * EMB + k0 + lk);
            acc[t] = __builtin_amdgcn_mfma_f32_16x16x32_f16(a, bf, acc[t], 0, 0, 0);
        }
    }
    // C layout (m89-verified): col = lane&15, row = (lane>>4)*4 + reg
    const int crow = (lane >> 4) * 4;
#pragma unroll
    for (int t = 0; t < 8; ++t) {
        const int col = n0 + t * 16 + lr;
        const float bv = bias[col];
#pragma unroll
        for (int r = 0; r < 4; ++r) {
            float v = acc[t][r] + bv;
            v = v > 0.f ? v : 0.f;
            OUT[(size_t)(m0 + crow + r) * HID + col] = (_Float16)v;
        }
    }
}

// ---------- attention: per (batch, 64-doc-row tile) ----------
// scores = Do_tile[64,768] . Qo[b][128,768]^T ; softmax over q ; out = attn . V[b]
__global__ __launch_bounds__(256) void attn_kernel(
    const _Float16* __restrict__ Do, const _Float16* __restrict__ Qo,
    const _Float16* __restrict__ VT, float* __restrict__ OUT) {
    __shared__ __align__(16) _Float16 lds_attn[64][136];  // pad: 272B stride -> 2-way (free)

    const int b = blockIdx.x;
    const int dblk = blockIdx.y;
    const int wave = threadIdx.x >> 6;
    const int lane = threadIdx.x & 63;
    const int lr = lane & 15;
    const int lk = (lane >> 4) * 8;

    // ---- Phase A: scores (8 q-tiles of 16) ----
    f32x4 s[8];
#pragma unroll
    for (int t = 0; t < 8; ++t) s[t] = (f32x4){0.f, 0.f, 0.f, 0.f};

    const _Float16* drow = Do + (size_t)(b * LD + dblk * 64 + wave * 16 + lr) * HID;
    const _Float16* qbase = Qo + (size_t)b * LQ * HID;
    for (int k0 = 0; k0 < HID; k0 += 32) {
        const f16x8 a = *(const f16x8*)(drow + k0 + lk);
#pragma unroll
        for (int t = 0; t < 8; ++t) {
            const f16x8 bf = *(const f16x8*)(qbase + (size_t)(t * 16 + lr) * HID + k0 + lk);
            s[t] = __builtin_amdgcn_mfma_f32_16x16x32_f16(a, bf, s[t], 0, 0, 0);
        }
    }

    // ---- Phase B/C: exact softmax over 128 per doc row; attn -> LDS (f16) ----
    // Lane holds cols q = t*16 + lr for rows (lane>>4)*4 + r. Row's 128 values live
    // on the 16 lanes sharing (lane>>4): reduce via shfl_xor 1,2,4,8 (stays in group).
#pragma unroll
    for (int r = 0; r < 4; ++r) {
        float m = -1e30f;
#pragma unroll
        for (int t = 0; t < 8; ++t) m = fmaxf(m, s[t][r]);
#pragma unroll
        for (int off = 1; off < 16; off <<= 1) m = fmaxf(m, __shfl_xor(m, off));
        float p[8];
        float sum = 0.f;
#pragma unroll
        for (int t = 0; t < 8; ++t) { p[t] = __expf(s[t][r] - m); sum += p[t]; }
#pragma unroll
        for (int off = 1; off < 16; off <<= 1) sum += __shfl_xor(sum, off);
        const float inv = 1.f / sum;
        const int row = wave * 16 + (lane >> 4) * 4 + r;
#pragma unroll
        for (int t = 0; t < 8; ++t) lds_attn[row][t * 16 + lr] = (_Float16)(p[t] * inv);
    }
    __syncthreads();

    // ---- Phase D: PV. out_tile[16,768] per wave, K = 128 (4 MFMA k-steps) ----
    const _Float16* vtb = VT + (size_t)b * EMB * LQ;
    const _Float16* arow = &lds_attn[wave * 16 + lr][0];
    const int dbase = b * LD + dblk * 64 + wave * 16 + (lane >> 4) * 4;
    for (int nc = 0; nc < 6; ++nc) {
        f32x4 o[8];
#pragma unroll
        for (int t = 0; t < 8; ++t) o[t] = (f32x4){0.f, 0.f, 0.f, 0.f};
#pragma unroll
        for (int ks = 0; ks < 4; ++ks) {
            const f16x8 a = *(const f16x8*)(arow + ks * 32 + lk);
#pragma unroll
            for (int t = 0; t < 8; ++t) {
                const f16x8 bf = *(const f16x8*)(vtb + (size_t)(nc * 128 + t * 16 + lr) * LQ + ks * 32 + lk);
                o[t] = __builtin_amdgcn_mfma_f32_16x16x32_f16(a, bf, o[t], 0, 0, 0);
            }
        }
#pragma unroll
        for (int t = 0; t < 8; ++t) {
            const int e = nc * 128 + t * 16 + lr;
#pragma unroll
            for (int r = 0; r < 4; ++r) {
                OUT[(size_t)(dbase + r) * EMB + e] = o[t][r];
            }
        }
    }
}

extern "C" void kernel_launch(void* const* d_in, const int* in_sizes, int n_in,
                              void* d_out, int out_size, void* d_ws, size_t ws_size,
                              hipStream_t stream) {
    const float* doc   = (const float*)d_in[0];   // [32,1024,768]
    const float* query = (const float*)d_in[1];   // [32,128,768]
    const float* W     = (const float*)d_in[2];   // [768,768]
    const float* bias  = (const float*)d_in[3];   // [768]
    float* out = (float*)d_out;                   // [32,1024,768] f32

    const size_t nW  = (size_t)HID * EMB;       // 589824
    const size_t nVT = (size_t)NB * EMB * LQ;   // 3145728
    const size_t nQo = (size_t)NB * LQ * HID;   // 3145728
    const size_t nDo = (size_t)NB * LD * HID;   // 25165824
    const size_t need = (nW + nVT + nQo + nDo) * sizeof(_Float16);  // ~64.1 MB
    if (ws_size < need) return;  // fail visibly (output stays poisoned) rather than OOB

    _Float16* W16 = (_Float16*)d_ws;
    _Float16* VT  = W16 + nW;
    _Float16* Qo  = VT + nVT;
    _Float16* Do  = Qo + nQo;

    cvt_w_kernel<<<(int)((nW + 255) / 256), 256, 0, stream>>>(W, W16, (int)nW);
    make_vt_kernel<<<(int)((nVT + 255) / 256), 256, 0, stream>>>(query, VT);
    proj_relu_kernel<<<dim3(NB * LQ / 64, HID / 128), 256, 0, stream>>>(query, W16, bias, Qo);
    proj_relu_kernel<<<dim3(NB * LD / 64, HID / 128), 256, 0, stream>>>(doc, W16, bias, Do);
    attn_kernel<<<dim3(NB, LD / 64), 256, 0, stream>>>(Do, Qo, VT, out);
}

// Round 2
// 160.144 us; speedup vs baseline: 3.2324x; 3.2324x over previous
//
#include <hip/hip_runtime.h>

typedef _Float16 f16x8 __attribute__((ext_vector_type(8)));
typedef float f32x4 __attribute__((ext_vector_type(4)));

#define EMB 768
#define LQ 128
#define LD 1024
#define NB 32

typedef const __attribute__((address_space(1))) char gas_char;
typedef __attribute__((address_space(3))) char las_char;

__device__ __forceinline__ void gload16(const void* g, void* l) {
    __builtin_amdgcn_global_load_lds((gas_char*)g, (las_char*)l, 16, 0, 0);
}

// XOR-swizzled halfword offset into a [128][64]-halfword LDS tile (16B chunks)
#define SWZ(row, ch) ((row) * 64 + ((((ch) ^ ((row) & 7))) * 8))

// Stage a 128-row x 64-halfword f16 tile (global row stride = 768 halfwords).
// Linear LDS dest (wave-uniform base + lane*16), inverse-swizzled global source.
__device__ __forceinline__ void stage_tile(const _Float16* g, _Float16* l, int wave, int lane) {
#pragma unroll
    for (int i = 0; i < 4; ++i) {
        const int idx = i * 256 + wave * 64 + lane;
        const int row = idx >> 3, ch = idx & 7;
        const int lch = ch ^ (row & 7);
        gload16(g + (size_t)row * EMB + lch * 8, l + (size_t)(i * 256 + wave * 64) * 8);
    }
}

// ---------- f32 -> f16, 8 elems/thread ----------
__global__ void cvt8_kernel(const float* __restrict__ in, _Float16* __restrict__ out, int n8) {
    int i = blockIdx.x * 256 + threadIdx.x;
    if (i >= n8) return;
    const float4 a = ((const float4*)in)[2 * i];
    const float4 b = ((const float4*)in)[2 * i + 1];
    f16x8 o;
    o[0] = (_Float16)a.x; o[1] = (_Float16)a.y; o[2] = (_Float16)a.z; o[3] = (_Float16)a.w;
    o[4] = (_Float16)b.x; o[5] = (_Float16)b.y; o[6] = (_Float16)b.z; o[7] = (_Float16)b.w;
    ((f16x8*)out)[i] = o;
}

// ---------- VT[b][e][q] = query_embed[b][q][e] (f16) ----------
__global__ void make_vt_kernel(const float* __restrict__ Q, _Float16* __restrict__ VT) {
    int i = blockIdx.x * 256 + threadIdx.x;
    if (i >= NB * EMB * LQ) return;
    int q = i % LQ;
    int e = (i / LQ) % EMB;
    int b = i / (LQ * EMB);
    VT[i] = (_Float16)Q[((size_t)b * LQ + q) * EMB + e];
}

// ---------- projection GEMM: OUT[m,h] = relu(A[m,:].W[h,:] + bias[h]), f16 out ----------
// 128x128 tile, BK=64, 4 waves (2x2), double-buffered LDS, one barrier per K-tile.
__global__ __launch_bounds__(256) void proj128_kernel(
    const _Float16* __restrict__ A, const _Float16* __restrict__ B,
    const float* __restrict__ bias, _Float16* __restrict__ OUT) {
    __shared__ __align__(16) _Float16 smem[32768];  // 2 x (A 8192 + B 8192) halfwords
    const int tid = threadIdx.x, wave = tid >> 6, lane = tid & 63;
    const int wr = wave >> 1, wc = wave & 1;
    const int lr = lane & 15, lkg = lane >> 4;
    const int row0 = blockIdx.x * 128, col0 = blockIdx.y * 128;
    const _Float16* ga = A + (size_t)row0 * EMB;
    const _Float16* gb = B + (size_t)col0 * EMB;

    f32x4 acc[4][4];
#pragma unroll
    for (int m = 0; m < 4; ++m)
#pragma unroll
        for (int n = 0; n < 4; ++n) acc[m][n] = (f32x4){0.f, 0.f, 0.f, 0.f};

    stage_tile(ga, smem, wave, lane);
    stage_tile(gb, smem + 8192, wave, lane);
    int cur = 0;
    for (int it = 0; it < 12; ++it) {
        __syncthreads();  // drains vmcnt: buf[cur] ready
        if (it < 11) {
            stage_tile(ga + (it + 1) * 64, smem + (cur ^ 1) * 16384, wave, lane);
            stage_tile(gb + (it + 1) * 64, smem + (cur ^ 1) * 16384 + 8192, wave, lane);
        }
        const _Float16* sA = smem + cur * 16384;
        const _Float16* sB = smem + cur * 16384 + 8192;
#pragma unroll
        for (int kk = 0; kk < 2; ++kk) {
            const int ch = kk * 4 + lkg;
            f16x8 af[4], bf[4];
#pragma unroll
            for (int m = 0; m < 4; ++m)
                af[m] = *(const f16x8*)(sA + SWZ(wr * 64 + m * 16 + lr, ch));
#pragma unroll
            for (int n = 0; n < 4; ++n)
                bf[n] = *(const f16x8*)(sB + SWZ(wc * 64 + n * 16 + lr, ch));
#pragma unroll
            for (int m = 0; m < 4; ++m)
#pragma unroll
                for (int n = 0; n < 4; ++n)
                    acc[m][n] = __builtin_amdgcn_mfma_f32_16x16x32_f16(af[m], bf[n], acc[m][n], 0, 0, 0);
        }
        cur ^= 1;
    }
    const int crow = lkg * 4;
#pragma unroll
    for (int n = 0; n < 4; ++n) {
        const int gc = col0 + wc * 64 + n * 16 + lr;
        const float bv = bias[gc];
#pragma unroll
        for (int m = 0; m < 4; ++m) {
            const size_t gr = row0 + wr * 64 + m * 16 + crow;
#pragma unroll
            for (int r = 0; r < 4; ++r) {
                float v = acc[m][n][r] + bv;
                OUT[(gr + r) * EMB + gc] = (_Float16)(v > 0.f ? v : 0.f);
            }
        }
    }
}

// ---------- attention: 128 doc rows/block, 4 waves x (32 rows x 128 q) ----------
__global__ __launch_bounds__(256) void attn128_kernel(
    const _Float16* __restrict__ Do, const _Float16* __restrict__ Qo,
    const _Float16* __restrict__ VT, float* __restrict__ OUT) {
    __shared__ __align__(16) _Float16 smem[32768];  // dbuf staging; P[128][136] aliases after
    const int tid = threadIdx.x, wave = tid >> 6, lane = tid & 63;
    const int lr = lane & 15, lkg = lane >> 4;
    const int b = blockIdx.x, dblk = blockIdx.y;
    const _Float16* gd = Do + ((size_t)b * LD + dblk * 128) * EMB;
    const _Float16* gq = Qo + (size_t)b * LQ * EMB;

    f32x4 s[2][8];
#pragma unroll
    for (int m = 0; m < 2; ++m)
#pragma unroll
        for (int n = 0; n < 8; ++n) s[m][n] = (f32x4){0.f, 0.f, 0.f, 0.f};

    stage_tile(gd, smem, wave, lane);
    stage_tile(gq, smem + 8192, wave, lane);
    int cur = 0;
    for (int it = 0; it < 12; ++it) {
        __syncthreads();
        if (it < 11) {
            stage_tile(gd + (it + 1) * 64, smem + (cur ^ 1) * 16384, wave, lane);
            stage_tile(gq + (it + 1) * 64, smem + (cur ^ 1) * 16384 + 8192, wave, lane);
        }
        const _Float16* sD = smem + cur * 16384;
        const _Float16* sQ = smem + cur * 16384 + 8192;
#pragma unroll
        for (int kk = 0; kk < 2; ++kk) {
            const int ch = kk * 4 + lkg;
            f16x8 am[2];
#pragma unroll
            for (int m = 0; m < 2; ++m)
                am[m] = *(const f16x8*)(sD + SWZ(wave * 32 + m * 16 + lr, ch));
#pragma unroll
            for (int n = 0; n < 8; ++n) {
                const f16x8 bq = *(const f16x8*)(sQ + SWZ(n * 16 + lr, ch));
#pragma unroll
                for (int m = 0; m < 2; ++m)
                    s[m][n] = __builtin_amdgcn_mfma_f32_16x16x32_f16(am[m], bq, s[m][n], 0, 0, 0);
            }
        }
        cur ^= 1;
    }
    __syncthreads();  // all staging-buffer reads done before P overwrites smem

    // exact softmax over 128 cols per doc row (16-lane-group shfl reduce), P -> LDS f16
    _Float16 (*P)[136] = (_Float16 (*)[136])smem;  // pad 8: 272B stride -> 2-way (free)
    const int crow = lkg * 4;
#pragma unroll
    for (int m = 0; m < 2; ++m) {
#pragma unroll
        for (int r = 0; r < 4; ++r) {
            float mx = -1e30f;
#pragma unroll
            for (int n = 0; n < 8; ++n) mx = fmaxf(mx, s[m][n][r]);
#pragma unroll
            for (int off = 1; off < 16; off <<= 1) mx = fmaxf(mx, __shfl_xor(mx, off));
            float p[8], sum = 0.f;
#pragma unroll
            for (int n = 0; n < 8; ++n) { p[n] = __expf(s[m][n][r] - mx); sum += p[n]; }
#pragma unroll
            for (int off = 1; off < 16; off <<= 1) sum += __shfl_xor(sum, off);
            const float inv = 1.f / sum;
            const int row = wave * 32 + m * 16 + crow + r;
#pragma unroll
            for (int n = 0; n < 8; ++n) P[row][n * 16 + lr] = (_Float16)(p[n] * inv);
        }
    }
    __syncthreads();

    // PV: out[128,768] = P[128,128] . V ; B-operand VT[e][q] direct from L2
    const _Float16* vtb = VT + (size_t)b * EMB * LQ;
#pragma unroll 1
    for (int nc = 0; nc < 6; ++nc) {
        f32x4 o[2][8];
#pragma unroll
        for (int m = 0; m < 2; ++m)
#pragma unroll
            for (int t = 0; t < 8; ++t) o[m][t] = (f32x4){0.f, 0.f, 0.f, 0.f};
#pragma unroll
        for (int ks = 0; ks < 4; ++ks) {
            f16x8 am[2];
#pragma unroll
            for (int m = 0; m < 2; ++m)
                am[m] = *(const f16x8*)(&P[wave * 32 + m * 16 + lr][ks * 32 + lkg * 8]);
#pragma unroll
            for (int t = 0; t < 8; ++t) {
                const f16x8 bv = *(const f16x8*)(vtb + (size_t)(nc * 128 + t * 16 + lr) * LQ + ks * 32 + lkg * 8);
#pragma unroll
                for (int m = 0; m < 2; ++m)
                    o[m][t] = __builtin_amdgcn_mfma_f32_16x16x32_f16(am[m], bv, o[m][t], 0, 0, 0);
            }
        }
#pragma unroll
        for (int t = 0; t < 8; ++t) {
#pragma unroll
            for (int m = 0; m < 2; ++m) {
                const size_t gr = (size_t)b * LD + dblk * 128 + wave * 32 + m * 16 + crow;
                const int e = nc * 128 + t * 16 + lr;
#pragma unroll
                for (int r = 0; r < 4; ++r)
                    OUT[(gr + r) * EMB + e] = o[m][t][r];
            }
        }
    }
}

extern "C" void kernel_launch(void* const* d_in, const int* in_sizes, int n_in,
                              void* d_out, int out_size, void* d_ws, size_t ws_size,
                              hipStream_t stream) {
    const float* doc   = (const float*)d_in[0];   // [32,1024,768]
    const float* query = (const float*)d_in[1];   // [32,128,768]
    const float* W     = (const float*)d_in[2];   // [768,768]
    const float* bias  = (const float*)d_in[3];   // [768]
    float* out = (float*)d_out;                   // [32,1024,768] f32

    const size_t nW  = (size_t)EMB * EMB;        // 589824
    const size_t nVT = (size_t)NB * EMB * LQ;    // 3145728
    const size_t nQo = (size_t)NB * LQ * EMB;    // 3145728
    const size_t nDo = (size_t)NB * LD * EMB;    // 25165824
    const size_t need = (nW + nVT + nQo + nDo) * sizeof(_Float16);  // ~64.1 MB (fits: proven round 1)
    if (ws_size < need) return;

    _Float16* W16 = (_Float16*)d_ws;
    _Float16* VT  = W16 + nW;
    _Float16* Qo  = VT + nVT;
    _Float16* Do  = Qo + nQo;

    // f16 copies of doc/query live in d_out (dead until attn writes it)
    _Float16* doc16 = (_Float16*)d_out;
    _Float16* q16   = doc16 + nDo;

    cvt8_kernel<<<(int)(nDo / 8 / 256), 256, 0, stream>>>(doc, doc16, (int)(nDo / 8));
    cvt8_kernel<<<(int)(nQo / 8 / 256), 256, 0, stream>>>(query, q16, (int)(nQo / 8));
    cvt8_kernel<<<(int)(nW / 8 / 256), 256, 0, stream>>>(W, W16, (int)(nW / 8));
    make_vt_kernel<<<(int)(nVT / 256), 256, 0, stream>>>(query, VT);

    proj128_kernel<<<dim3(NB * LQ / 128, EMB / 128), 256, 0, stream>>>(q16, W16, bias, Qo);
    proj128_kernel<<<dim3(NB * LD / 128, EMB / 128), 256, 0, stream>>>(doc16, W16, bias, Do);
    attn128_kernel<<<dim3(NB, LD / 128), 256, 0, stream>>>(Do, Qo, VT, out);
}